// Round 4
// baseline (333.115 us; speedup 1.0000x reference)
//
#include <hip/hip_runtime.h>

// B=4, N=2048, C=256, ic=128.  Algebra (validated rounds 1-5):
//   T=lin(aim,theta) P=lin(detect,phi) Gd=lin(detect,g) Ga=lin(aim,g2)   [bf16]
//   X_v := per-batch view [128,4096] of [2048,256] (pure reshape)
//   S_aT = Gd_v @ P_v^T ; S_bT = Ga_v @ T_v^T        [128,128] fp32 (split-K + reduce)
//   out_aim[r,d] = (1/4096)*sum_k S_aT[r/16,k]*TW[16k+(r%16),d] + Wb[d] + aim[r,d]
//   with TW = T @ W^T  (and symmetrically out_det from S_bT, PQ = P @ Q^T).
// Round 7: round-6 mega-kernel, but NORMAL launch + manual grid barrier.
//   hipLaunchCooperativeKernel was silently rejected under graph capture
//   (round-6 absmax == max|ref| == launch never ran). Replacement:
//   - 512 blocks x 256 thr, __launch_bounds__(256,2) -> 2 blocks/CU capacity
//     => all 512 co-resident (grid == capacity) => barrier cannot deadlock.
//   - barrier: device-scope atomics in ws + __threadfence() both sides
//     (Guideline 16 mechanism); counters zeroed per replay by hipMemsetAsync.

typedef __attribute__((ext_vector_type(4))) float  f32x4;
typedef __attribute__((ext_vector_type(8))) __bf16 bf16x8;
typedef __attribute__((ext_vector_type(8))) unsigned short u16x8;
typedef __attribute__((ext_vector_type(4))) unsigned short u16x4;

__device__ inline unsigned short f2bf(float f) {
    union { float f; unsigned u; } c; c.f = f;
    unsigned r = c.u + 0x7FFF + ((c.u >> 16) & 1);   // RNE
    return (unsigned short)(r >> 16);
}
__device__ inline bf16x8 ldfrag(const unsigned short* p) {
    return __builtin_bit_cast(bf16x8, *(const u16x8*)p);
}

#define NBLK 512u

__device__ inline void gridbar(unsigned* bar, int slot) {
    __syncthreads();
    if (threadIdx.x == 0) {
        __threadfence();   // release: drain writes, wb L2 (agent scope)
        __hip_atomic_fetch_add(bar + slot, 1u, __ATOMIC_RELAXED, __HIP_MEMORY_SCOPE_AGENT);
        while (__hip_atomic_load(bar + slot, __ATOMIC_RELAXED, __HIP_MEMORY_SCOPE_AGENT) < NBLK)
            __builtin_amdgcn_s_sleep(8);
        __threadfence();   // acquire: inv L1/L2 (agent scope)
    }
    __syncthreads();
}

struct MegaArgs {
    const float *detect, *aim;
    const float *g_w, *g2_w, *th_w, *ph_w, *W_w, *Q_w;
    const float *b_g, *b_g2, *b_th, *b_ph, *b_W, *b_Q;
    unsigned short *Wbf, *Abf, *Dbf, *T, *P, *Gd, *Ga, *TW, *PQ, *Sbf;
    float *Spart, *out_aim, *out_det;
    unsigned *bar;
};

__global__ __launch_bounds__(256, 2)
void mega_kernel(MegaArgs a)
{
    // 27648 B, reused across phases:
    //   lin4  As[64][40]+Bs[256][40]=25600B | twpq As[64][40]+Bs[128][40]=15360B
    //   s_part As[64][72]+Bs[64][72]=18432B | combine As[64][72]+Bs[128][72]=27648B
    __shared__ unsigned short lds[13824];

    const int bid = blockIdx.x, tid = threadIdx.x;
    const int lane = tid & 63, w = tid >> 6;
    const int wr = w >> 1, wc = w & 1, q = lane >> 4, ln = lane & 15;

    // ================= P0: fp32 -> bf16 convert =================
    // weights: blocks 0-43 (98304 float4); aim: 44-277; detect: 278-511 (524288 each).
    if (bid < 44) {
        for (int i = bid * 256 + tid; i < 98304; i += 44 * 256) {
            int wsel = i >> 14, off = i & 16383;
            const float* src = wsel == 0 ? a.g_w : wsel == 1 ? a.g2_w : wsel == 2 ? a.th_w :
                               wsel == 3 ? a.ph_w : wsel == 4 ? a.W_w : a.Q_w;
            float4 v = ((const float4*)src)[off];
            u16x4 p; p[0]=f2bf(v.x); p[1]=f2bf(v.y); p[2]=f2bf(v.z); p[3]=f2bf(v.w);
            ((u16x4*)(a.Wbf + (size_t)wsel * 65536))[off] = p;
        }
    } else {
        const int r = bid - 44;
        const float* src = r < 234 ? a.aim : a.detect;
        unsigned short* o = r < 234 ? a.Abf : a.Dbf;
        const int rb = r < 234 ? r : r - 234;
        for (int i = rb * 256 + tid; i < 524288; i += 234 * 256) {
            float4 v = ((const float4*)src)[i];
            u16x4 p; p[0]=f2bf(v.x); p[1]=f2bf(v.y); p[2]=f2bf(v.z); p[3]=f2bf(v.w);
            ((u16x4*)o)[i] = p;
        }
    }
    gridbar(a.bar, 0);

    // ================= P1: four input linears =================
    // 512 jobs: z = bid>>8 (0:aim,1:detect), set = bid&1, mtile = (bid&255)>>1.
    {
        const int z = bid >> 8, rem = bid & 255, set = rem & 1, mtile = rem >> 1;
        const unsigned short* Ap = z ? a.Dbf : a.Abf;
        const int wslot = z ? (set ? 0 : 3) : (set ? 1 : 2);   // g / ph / g2 / th
        const unsigned short* Wm = a.Wbf + (size_t)wslot * 65536;
        const float* Bv = z ? (set ? a.b_g : a.b_ph) : (set ? a.b_g2 : a.b_th);
        unsigned short* O = z ? (set ? a.Gd : a.P) : (set ? a.Ga : a.T);
        const int m0 = mtile * 64;

        unsigned short (*As)[40] = (unsigned short (*)[40])lds;               // [64][40]
        unsigned short (*Bs)[40] = (unsigned short (*)[40])(lds + 64 * 40);   // [256][40]

        f32x4 acc[2][8] = {};

        for (int k0 = 0; k0 < 256; k0 += 32) {
            {                                        // A: 64x32 bf16 = 256 u16x8
                int row = tid >> 2, c8 = tid & 3;
                *(u16x8*)&As[row][c8 * 8] = *(const u16x8*)(Ap + (size_t)(m0 + row) * 256 + k0 + c8 * 8);
            }
            #pragma unroll
            for (int i = 0; i < 4; ++i) {            // W: 256x32 bf16 = 1024 u16x8
                int c = tid + i * 256, row = c >> 2, c8 = c & 3;
                *(u16x8*)&Bs[row][c8 * 8] = *(const u16x8*)(Wm + (size_t)row * 256 + k0 + c8 * 8);
            }
            __syncthreads();
            bf16x8 af[2], bb[8];
            #pragma unroll
            for (int i = 0; i < 2; ++i) af[i] = ldfrag(&As[wr * 32 + i * 16 + ln][q * 8]);
            #pragma unroll
            for (int j = 0; j < 8; ++j) bb[j] = ldfrag(&Bs[wc * 128 + j * 16 + ln][q * 8]);
            #pragma unroll
            for (int i = 0; i < 2; ++i)
                #pragma unroll
                for (int j = 0; j < 8; ++j)
                    acc[i][j] = __builtin_amdgcn_mfma_f32_16x16x32_bf16(af[i], bb[j], acc[i][j], 0, 0, 0);
            __syncthreads();
        }

        #pragma unroll
        for (int i = 0; i < 2; ++i)
            #pragma unroll
            for (int j = 0; j < 8; ++j) {
                int n = wc * 128 + j * 16 + ln;
                float bias = Bv[n];
                #pragma unroll
                for (int r = 0; r < 4; ++r) {
                    int m = m0 + wr * 32 + i * 16 + q * 4 + r;
                    O[(size_t)m * 256 + n] = f2bf(acc[i][j][r] + bias);
                }
            }
    }
    gridbar(a.bar, 1);

    // ================= P2a: TW/PQ GEMM (64x128, K=256) =================
    // 512 jobs: side = bid>>8 (0:TW=T@W^T, 1:PQ=P@Q^T), mtile=(bid&255)>>1, nhalf=bid&1.
    {
        const int side = bid >> 8, rem = bid & 255, mtile = rem >> 1, nhalf = rem & 1;
        const unsigned short* Ap = side ? a.P : a.T;
        const unsigned short* Wm = a.Wbf + (size_t)(4 + side) * 65536;
        unsigned short* O = side ? a.PQ : a.TW;
        const int m0 = mtile * 64, n0 = nhalf * 128;

        unsigned short (*As)[40] = (unsigned short (*)[40])lds;               // [64][40]
        unsigned short (*Bs)[40] = (unsigned short (*)[40])(lds + 64 * 40);   // [128][40]

        f32x4 acc[2][4] = {};

        for (int k0 = 0; k0 < 256; k0 += 32) {
            {                                        // A: 64x32 bf16 = 256 u16x8
                int row = tid >> 2, c8 = tid & 3;
                *(u16x8*)&As[row][c8 * 8] = *(const u16x8*)(Ap + (size_t)(m0 + row) * 256 + k0 + c8 * 8);
            }
            #pragma unroll
            for (int i = 0; i < 2; ++i) {            // W: 128x32 bf16 = 512 u16x8
                int c = tid + i * 256, row = c >> 2, c8 = c & 3;
                *(u16x8*)&Bs[row][c8 * 8] = *(const u16x8*)(Wm + (size_t)(n0 + row) * 256 + k0 + c8 * 8);
            }
            __syncthreads();
            bf16x8 af[2], bb[4];
            #pragma unroll
            for (int i = 0; i < 2; ++i) af[i] = ldfrag(&As[wr * 32 + i * 16 + ln][q * 8]);
            #pragma unroll
            for (int j = 0; j < 4; ++j) bb[j] = ldfrag(&Bs[wc * 64 + j * 16 + ln][q * 8]);
            #pragma unroll
            for (int i = 0; i < 2; ++i)
                #pragma unroll
                for (int j = 0; j < 4; ++j)
                    acc[i][j] = __builtin_amdgcn_mfma_f32_16x16x32_bf16(af[i], bb[j], acc[i][j], 0, 0, 0);
            __syncthreads();
        }

        #pragma unroll
        for (int i = 0; i < 2; ++i)
            #pragma unroll
            for (int j = 0; j < 4; ++j) {
                int n = n0 + wc * 64 + j * 16 + ln;
                #pragma unroll
                for (int r = 0; r < 4; ++r) {
                    int m = m0 + wr * 32 + i * 16 + q * 4 + r;
                    O[(size_t)m * 256 + n] = f2bf(acc[i][j][r]);
                }
            }
    }

    // ================= P2b: S partials (64x64 tile, KC=256) =================
    // 512 jobs: which = bid>>8, batch=(bid>>6)&3, mt, nt, chunk (16).
    {
        const int which = bid >> 8, rem = bid & 255, batch = rem >> 6, rem2 = rem & 63;
        const int mt = rem2 >> 5, nt = (rem2 >> 4) & 1, chunk = rem2 & 15;
        const unsigned short* Ap = (which ? a.Ga : a.Gd) + (size_t)batch * 524288;
        const unsigned short* Bp = (which ? a.T  : a.P ) + (size_t)batch * 524288;
        float* out = a.Spart + ((size_t)(which * 4 + batch) * 16 + chunk) * 16384;
        const int kbeg = chunk * 256, m0 = mt * 64, n0 = nt * 64;

        unsigned short (*As)[72] = (unsigned short (*)[72])lds;               // [64][72]
        unsigned short (*Bs)[72] = (unsigned short (*)[72])(lds + 64 * 72);   // [64][72]

        f32x4 acc[2][2] = {};

        for (int kk = 0; kk < 4; ++kk) {
            const int k0 = kbeg + kk * 64;
            #pragma unroll
            for (int i = 0; i < 2; ++i) {            // A,B: 64x64 bf16 = 512 u16x8 each
                int c = tid + i * 256, row = c >> 3, c8 = c & 7;
                *(u16x8*)&As[row][c8 * 8] = *(const u16x8*)(Ap + (size_t)(m0 + row) * 4096 + k0 + c8 * 8);
                *(u16x8*)&Bs[row][c8 * 8] = *(const u16x8*)(Bp + (size_t)(n0 + row) * 4096 + k0 + c8 * 8);
            }
            __syncthreads();
            #pragma unroll
            for (int ks = 0; ks < 2; ++ks) {
                bf16x8 af[2], bb[2];
                #pragma unroll
                for (int i = 0; i < 2; ++i) af[i] = ldfrag(&As[wr * 32 + i * 16 + ln][ks * 32 + q * 8]);
                #pragma unroll
                for (int j = 0; j < 2; ++j) bb[j] = ldfrag(&Bs[wc * 32 + j * 16 + ln][ks * 32 + q * 8]);
                #pragma unroll
                for (int i = 0; i < 2; ++i)
                    #pragma unroll
                    for (int j = 0; j < 2; ++j)
                        acc[i][j] = __builtin_amdgcn_mfma_f32_16x16x32_bf16(af[i], bb[j], acc[i][j], 0, 0, 0);
            }
            __syncthreads();
        }

        #pragma unroll
        for (int i = 0; i < 2; ++i)
            #pragma unroll
            for (int j = 0; j < 2; ++j)
                #pragma unroll
                for (int r = 0; r < 4; ++r) {
                    int m = m0 + wr * 32 + i * 16 + q * 4 + r, n = n0 + wc * 32 + j * 16 + ln;
                    out[m * 128 + n] = acc[i][j][r];
                }
    }
    gridbar(a.bar, 2);

    // ================= P3: reduce S partials -> bf16, pre-scaled =================
    {
        const int idx = bid * 256 + tid;                 // 131072 outputs
        const int c = idx >> 14, e = idx & 16383;
        float s = 0.f;
        #pragma unroll
        for (int k = 0; k < 16; ++k) s += a.Spart[((size_t)(c * 16 + k) << 14) + e];
        a.Sbf[idx] = f2bf(s * (1.0f / 4096.0f));
    }
    gridbar(a.bar, 3);

    // ================= P4: combine  out = S~ @ TW_q + bias + residual =================
    // 512 jobs: which=bid>>8, batch=(bid>>6)&3, qq=(bid>>2)&15, dtile=(bid>>1)&1, ihalf=bid&1.
    {
        const int which = bid >> 8, batch = (bid >> 6) & 3, qq = (bid >> 2) & 15;
        const int dtile = (bid >> 1) & 1, ihalf = bid & 1;
        const int d0 = dtile * 128, i0 = ihalf * 64;
        const unsigned short* Sm = a.Sbf + (size_t)(which * 4 + batch) * 16384;
        const unsigned short* Bsrc = (which ? a.PQ : a.TW) + (size_t)batch * 524288;
        const float* Bv = which ? a.b_Q : a.b_W;
        const float* R  = (which ? a.detect : a.aim) + (size_t)batch * 524288;
        float* O = (which ? a.out_det : a.out_aim) + (size_t)batch * 524288;

        unsigned short (*As)[72] = (unsigned short (*)[72])lds;               // [64][72]
        unsigned short (*Bs)[72] = (unsigned short (*)[72])(lds + 64 * 72);   // [128][72]

        f32x4 acc[2][4] = {};

        for (int kk = 0; kk < 2; ++kk) {
            const int k0 = kk * 64;
            #pragma unroll
            for (int i = 0; i < 2; ++i) {            // A: 64x64 bf16 = 512 u16x8
                int c = tid + i * 256, row = c >> 3, c8 = c & 7;
                *(u16x8*)&As[row][c8 * 8] = *(const u16x8*)(Sm + (size_t)(i0 + row) * 128 + k0 + c8 * 8);
            }
            #pragma unroll
            for (int i = 0; i < 4; ++i) {            // B: gather 64 rows 16k+q, transpose to [d][k]
                int c = tid + i * 256, krow = c >> 4, dc = (c & 15) * 8;
                int gr = 16 * (k0 + krow) + qq;
                u16x8 v = *(const u16x8*)(Bsrc + (size_t)gr * 256 + d0 + dc);
                #pragma unroll
                for (int jj = 0; jj < 8; ++jj) Bs[dc + jj][krow] = v[jj];
            }
            __syncthreads();
            #pragma unroll
            for (int ks = 0; ks < 2; ++ks) {
                bf16x8 af[2], bb[4];
                #pragma unroll
                for (int i = 0; i < 2; ++i) af[i] = ldfrag(&As[wr * 32 + i * 16 + ln][ks * 32 + q * 8]);
                #pragma unroll
                for (int j = 0; j < 4; ++j) bb[j] = ldfrag(&Bs[wc * 64 + j * 16 + ln][ks * 32 + q * 8]);
                #pragma unroll
                for (int i = 0; i < 2; ++i)
                    #pragma unroll
                    for (int j = 0; j < 4; ++j)
                        acc[i][j] = __builtin_amdgcn_mfma_f32_16x16x32_bf16(af[i], bb[j], acc[i][j], 0, 0, 0);
            }
            __syncthreads();
        }

        #pragma unroll
        for (int i = 0; i < 2; ++i)
            #pragma unroll
            for (int j = 0; j < 4; ++j) {
                int d = d0 + wc * 64 + j * 16 + ln;
                float bias = Bv[d];
                #pragma unroll
                for (int r = 0; r < 4; ++r) {
                    int iS = i0 + wr * 32 + i * 16 + q * 4 + r;
                    size_t off = (size_t)(16 * iS + qq) * 256 + d;
                    O[off] = acc[i][j][r] + bias + R[off];
                }
            }
    }
}

extern "C" void kernel_launch(void* const* d_in, const int* in_sizes, int n_in,
                              void* d_out, int out_size, void* d_ws, size_t ws_size,
                              hipStream_t stream)
{
    const size_t TOT = 8192L * 256;   // 2,097,152 elems per tensor

    unsigned short* ws16 = (unsigned short*)d_ws;
    unsigned short* Wbf = ws16;                 // [6][65536]: g,g2,th,ph,W,Q
    unsigned short* Abf = Wbf + 6 * 65536;      // aim bf16
    unsigned short* Dbf = Abf + TOT;            // detect bf16
    unsigned short* T   = Dbf + TOT;
    unsigned short* P   = T  + TOT;
    unsigned short* Gd  = P  + TOT;
    unsigned short* Ga  = Gd + TOT;
    unsigned short* TW  = Ga + TOT;             // T @ W^T  bf16 [8192,256]
    unsigned short* PQ  = TW + TOT;             // P @ Q^T  bf16 [8192,256]
    unsigned short* Sbf = PQ + TOT;             // [2][4][128][128] bf16 (pre-scaled)
    float* Spart = (float*)(Sbf + 131072);      // [2][4][16][128][128] fp32
    unsigned* bar = (unsigned*)(Spart + (size_t)2 * 4 * 16 * 16384);

    float* out_det = (float*)d_out;
    float* out_aim = out_det + TOT;

    MegaArgs h;
    h.detect = (const float*)d_in[0];
    h.aim    = (const float*)d_in[1];
    h.g_w  = (const float*)d_in[2];  h.b_g  = (const float*)d_in[3];
    h.g2_w = (const float*)d_in[4];  h.b_g2 = (const float*)d_in[5];
    h.th_w = (const float*)d_in[6];  h.b_th = (const float*)d_in[7];
    h.ph_w = (const float*)d_in[8];  h.b_ph = (const float*)d_in[9];
    h.W_w  = (const float*)d_in[10]; h.b_W  = (const float*)d_in[11];
    h.Q_w  = (const float*)d_in[12]; h.b_Q  = (const float*)d_in[13];
    h.Wbf = Wbf; h.Abf = Abf; h.Dbf = Dbf; h.T = T; h.P = P;
    h.Gd = Gd; h.Ga = Ga; h.TW = TW; h.PQ = PQ; h.Sbf = Sbf;
    h.Spart = Spart; h.out_aim = out_aim; h.out_det = out_det;
    h.bar = bar;

    hipMemsetAsync(bar, 0, 64, stream);          // zero barrier slots (capture-legal)
    mega_kernel<<<dim3(512), dim3(256), 0, stream>>>(h);
}

// Round 5
// 199.974 us; speedup vs baseline: 1.6658x; 1.6658x over previous
//
#include <hip/hip_runtime.h>

// B=4, N=2048, C=256, ic=128.  Algebra (validated rounds 1-7):
//   T=lin(aim,theta) P=lin(detect,phi) Gd=lin(detect,g) Ga=lin(aim,g2)   [bf16]
//   X_v := per-batch view [128,4096] of [2048,256] (pure reshape)
//   S_aT = Gd_v @ P_v^T ; S_bT = Ga_v @ T_v^T        [128,128] fp32
//   out_aim[r,d] = (1/4096)*sum_k S_aT[r/16,k]*TW[16k+(r%16),d] + Wb[d] + aim[r,d]
//   with TW = T @ W^T  (and symmetrically out_det from S_bT, PQ = P @ Q^T).
// Round 8: mega-kernel kept, barrier redesigned + phases compressed.
//   Round-7 ran correct but 240 us at 1.4% util: 512 fetch_adds to ONE line
//   + 511 pollers on the same line = coherence storm (~50 us/barrier x 4).
//   Fixes:
//   - barrier: per-block flag array (write-once, distinct words) + block-0
//     poll + single release word. No RMW contention, read-shared polling.
//   - 4 barriers -> 2: fp32->bf16 prep folded into P1/P2a staging (P0 gone,
//     Wbf/Abf/Dbf gone); sred gone (s_part unsafeAtomicAdd's fp32 partials
//     into S; combine converts S during staging).

typedef __attribute__((ext_vector_type(4))) float  f32x4;
typedef __attribute__((ext_vector_type(8))) __bf16 bf16x8;
typedef __attribute__((ext_vector_type(8))) unsigned short u16x8;
typedef __attribute__((ext_vector_type(4))) unsigned short u16x4;

__device__ inline unsigned short f2bf(float f) {
    union { float f; unsigned u; } c; c.f = f;
    unsigned r = c.u + 0x7FFF + ((c.u >> 16) & 1);   // RNE
    return (unsigned short)(r >> 16);
}
__device__ inline bf16x8 ldfrag(const unsigned short* p) {
    return __builtin_bit_cast(bf16x8, *(const u16x8*)p);
}

// Contention-free grid barrier. Region layout (per barrier, 1024 uints):
//   [0..511]  per-block arrival flags (write-once)
//   [768]     release word (write-once)
// All 512 blocks co-resident (grid == 2/CU capacity, __launch_bounds__(256,2))
// => cannot deadlock. Flags/release zeroed per launch by hipMemsetAsync.
__device__ inline void gridbar(unsigned* b) {
    __syncthreads();
    const int tid = threadIdx.x;
    if (blockIdx.x == 0) {
        if (tid > 0) {                     // poll blocks 1..255
            while (__hip_atomic_load(b + tid, __ATOMIC_RELAXED, __HIP_MEMORY_SCOPE_AGENT) == 0)
                __builtin_amdgcn_s_sleep(16);
        }
        while (__hip_atomic_load(b + 256 + tid, __ATOMIC_RELAXED, __HIP_MEMORY_SCOPE_AGENT) == 0)
            __builtin_amdgcn_s_sleep(16);  // poll blocks 256..511
        __syncthreads();
        if (tid == 0) {
            __threadfence();               // full fence: release own writes, acquire others'
            __hip_atomic_store(b + 768, 1u, __ATOMIC_RELAXED, __HIP_MEMORY_SCOPE_AGENT);
        }
        __syncthreads();
    } else {
        if (tid == 0) {
            __threadfence();               // release this block's phase writes
            __hip_atomic_store(b + blockIdx.x, 1u, __ATOMIC_RELAXED, __HIP_MEMORY_SCOPE_AGENT);
            while (__hip_atomic_load(b + 768, __ATOMIC_RELAXED, __HIP_MEMORY_SCOPE_AGENT) == 0)
                __builtin_amdgcn_s_sleep(16);
            __threadfence();               // acquire
        }
        __syncthreads();
    }
}

struct MegaArgs {
    const float *detect, *aim;
    const float *g_w, *g2_w, *th_w, *ph_w, *W_w, *Q_w;
    const float *b_g, *b_g2, *b_th, *b_ph, *b_W, *b_Q;
    unsigned short *T, *P, *Gd, *Ga, *TW, *PQ;
    float *S;                 // [2][4][128][128] fp32, atomically accumulated
    float *out_aim, *out_det;
    unsigned *bar;            // 2 x 1024 uints
};

__global__ __launch_bounds__(256, 2)
void mega_kernel(MegaArgs a)
{
    // 27648 B, reused across phases:
    //   P1  As[64][40]+Bs[256][40]=25600B | P2a As[64][40]+Bs[128][40]=15360B
    //   P2b As[64][72]+Bs[64][72]=18432B  | P4  As[64][72]+Bs[128][72]=27648B
    __shared__ unsigned short lds[13824];

    const int bid = blockIdx.x, tid = threadIdx.x;
    const int lane = tid & 63, w = tid >> 6;
    const int wr = w >> 1, wc = w & 1, q = lane >> 4, ln = lane & 15;

    // ================= P1: four input linears (fp32 inputs, inline convert) ==
    // 512 jobs: z = bid>>8 (0:aim,1:detect), set = bid&1, mtile = (bid&255)>>1.
    {
        const int z = bid >> 8, rem = bid & 255, set = rem & 1, mtile = rem >> 1;
        const float* Ap = z ? a.detect : a.aim;
        const float* Wm = z ? (set ? a.g_w : a.ph_w) : (set ? a.g2_w : a.th_w);
        const float* Bv = z ? (set ? a.b_g : a.b_ph) : (set ? a.b_g2 : a.b_th);
        unsigned short* O = z ? (set ? a.Gd : a.P) : (set ? a.Ga : a.T);
        const int m0 = mtile * 64;

        unsigned short (*As)[40] = (unsigned short (*)[40])lds;               // [64][40]
        unsigned short (*Bs)[40] = (unsigned short (*)[40])(lds + 64 * 40);   // [256][40]

        f32x4 acc[2][8] = {};

        for (int k0 = 0; k0 < 256; k0 += 32) {
            #pragma unroll
            for (int i = 0; i < 2; ++i) {            // A: 64x32 fp32 = 512 float4
                int idx = tid + i * 256, row = idx >> 3, c4 = idx & 7;
                float4 v = *(const float4*)(Ap + (size_t)(m0 + row) * 256 + k0 + c4 * 4);
                u16x4 p; p[0]=f2bf(v.x); p[1]=f2bf(v.y); p[2]=f2bf(v.z); p[3]=f2bf(v.w);
                *(u16x4*)&As[row][c4 * 4] = p;
            }
            #pragma unroll
            for (int i = 0; i < 8; ++i) {            // W: 256x32 fp32 = 2048 float4
                int idx = tid + i * 256, row = idx >> 3, c4 = idx & 7;
                float4 v = *(const float4*)(Wm + (size_t)row * 256 + k0 + c4 * 4);
                u16x4 p; p[0]=f2bf(v.x); p[1]=f2bf(v.y); p[2]=f2bf(v.z); p[3]=f2bf(v.w);
                *(u16x4*)&Bs[row][c4 * 4] = p;
            }
            __syncthreads();
            bf16x8 af[2], bb[8];
            #pragma unroll
            for (int i = 0; i < 2; ++i) af[i] = ldfrag(&As[wr * 32 + i * 16 + ln][q * 8]);
            #pragma unroll
            for (int j = 0; j < 8; ++j) bb[j] = ldfrag(&Bs[wc * 128 + j * 16 + ln][q * 8]);
            #pragma unroll
            for (int i = 0; i < 2; ++i)
                #pragma unroll
                for (int j = 0; j < 8; ++j)
                    acc[i][j] = __builtin_amdgcn_mfma_f32_16x16x32_bf16(af[i], bb[j], acc[i][j], 0, 0, 0);
            __syncthreads();
        }

        #pragma unroll
        for (int i = 0; i < 2; ++i)
            #pragma unroll
            for (int j = 0; j < 8; ++j) {
                int n = wc * 128 + j * 16 + ln;
                float bias = Bv[n];
                #pragma unroll
                for (int r = 0; r < 4; ++r) {
                    int m = m0 + wr * 32 + i * 16 + q * 4 + r;
                    O[(size_t)m * 256 + n] = f2bf(acc[i][j][r] + bias);
                }
            }
    }
    gridbar(a.bar);

    // ================= P2a: TW/PQ GEMM (64x128, K=256; W from fp32) =========
    // 512 jobs: side = bid>>8 (0:TW=T@W^T, 1:PQ=P@Q^T), mtile=(bid&255)>>1, nhalf=bid&1.
    {
        const int side = bid >> 8, rem = bid & 255, mtile = rem >> 1, nhalf = rem & 1;
        const unsigned short* Ap = side ? a.P : a.T;
        const float* Wm = side ? a.Q_w : a.W_w;
        unsigned short* O = side ? a.PQ : a.TW;
        const int m0 = mtile * 64, n0 = nhalf * 128;

        unsigned short (*As)[40] = (unsigned short (*)[40])lds;               // [64][40]
        unsigned short (*Bs)[40] = (unsigned short (*)[40])(lds + 64 * 40);   // [128][40]

        f32x4 acc[2][4] = {};

        for (int k0 = 0; k0 < 256; k0 += 32) {
            {                                        // A: 64x32 bf16 = 256 u16x8
                int row = tid >> 2, c8 = tid & 3;
                *(u16x8*)&As[row][c8 * 8] = *(const u16x8*)(Ap + (size_t)(m0 + row) * 256 + k0 + c8 * 8);
            }
            #pragma unroll
            for (int i = 0; i < 4; ++i) {            // W: 128x32 fp32 = 1024 float4
                int idx = tid + i * 256, row = idx >> 3, c4 = idx & 7;
                float4 v = *(const float4*)(Wm + (size_t)(n0 + row) * 256 + k0 + c4 * 4);
                u16x4 p; p[0]=f2bf(v.x); p[1]=f2bf(v.y); p[2]=f2bf(v.z); p[3]=f2bf(v.w);
                *(u16x4*)&Bs[row][c4 * 4] = p;
            }
            __syncthreads();
            bf16x8 af[2], bb[4];
            #pragma unroll
            for (int i = 0; i < 2; ++i) af[i] = ldfrag(&As[wr * 32 + i * 16 + ln][q * 8]);
            #pragma unroll
            for (int j = 0; j < 4; ++j) bb[j] = ldfrag(&Bs[wc * 64 + j * 16 + ln][q * 8]);
            #pragma unroll
            for (int i = 0; i < 2; ++i)
                #pragma unroll
                for (int j = 0; j < 4; ++j)
                    acc[i][j] = __builtin_amdgcn_mfma_f32_16x16x32_bf16(af[i], bb[j], acc[i][j], 0, 0, 0);
            __syncthreads();
        }

        #pragma unroll
        for (int i = 0; i < 2; ++i)
            #pragma unroll
            for (int j = 0; j < 4; ++j) {
                int n = n0 + wc * 64 + j * 16 + ln;
                #pragma unroll
                for (int r = 0; r < 4; ++r) {
                    int m = m0 + wr * 32 + i * 16 + q * 4 + r;
                    O[(size_t)m * 256 + n] = f2bf(acc[i][j][r]);
                }
            }
    }

    // ================= P2b: S partials (64x64, KC=256) -> atomic into S ======
    // 512 jobs: which=bid>>8, batch=(bid>>6)&3, mt, nt, chunk(16).
    {
        const int which = bid >> 8, rem = bid & 255, batch = rem >> 6, rem2 = rem & 63;
        const int mt = rem2 >> 5, nt = (rem2 >> 4) & 1, chunk = rem2 & 15;
        const unsigned short* Ap = (which ? a.Ga : a.Gd) + (size_t)batch * 524288;
        const unsigned short* Bp = (which ? a.T  : a.P ) + (size_t)batch * 524288;
        float* Sp = a.S + ((size_t)(which * 4 + batch) << 14);
        const int kbeg = chunk * 256, m0 = mt * 64, n0 = nt * 64;

        unsigned short (*As)[72] = (unsigned short (*)[72])lds;               // [64][72]
        unsigned short (*Bs)[72] = (unsigned short (*)[72])(lds + 64 * 72);   // [64][72]

        f32x4 acc[2][2] = {};

        for (int kk = 0; kk < 4; ++kk) {
            const int k0 = kbeg + kk * 64;
            #pragma unroll
            for (int i = 0; i < 2; ++i) {            // A,B: 64x64 bf16 = 512 u16x8 each
                int c = tid + i * 256, row = c >> 3, c8 = c & 7;
                *(u16x8*)&As[row][c8 * 8] = *(const u16x8*)(Ap + (size_t)(m0 + row) * 4096 + k0 + c8 * 8);
                *(u16x8*)&Bs[row][c8 * 8] = *(const u16x8*)(Bp + (size_t)(n0 + row) * 4096 + k0 + c8 * 8);
            }
            __syncthreads();
            #pragma unroll
            for (int ks = 0; ks < 2; ++ks) {
                bf16x8 af[2], bb[2];
                #pragma unroll
                for (int i = 0; i < 2; ++i) af[i] = ldfrag(&As[wr * 32 + i * 16 + ln][ks * 32 + q * 8]);
                #pragma unroll
                for (int j = 0; j < 2; ++j) bb[j] = ldfrag(&Bs[wc * 32 + j * 16 + ln][ks * 32 + q * 8]);
                #pragma unroll
                for (int i = 0; i < 2; ++i)
                    #pragma unroll
                    for (int j = 0; j < 2; ++j)
                        acc[i][j] = __builtin_amdgcn_mfma_f32_16x16x32_bf16(af[i], bb[j], acc[i][j], 0, 0, 0);
            }
            __syncthreads();
        }

        #pragma unroll
        for (int i = 0; i < 2; ++i)
            #pragma unroll
            for (int j = 0; j < 2; ++j)
                #pragma unroll
                for (int r = 0; r < 4; ++r) {
                    int m = m0 + wr * 32 + i * 16 + q * 4 + r, n = n0 + wc * 32 + j * 16 + ln;
                    unsafeAtomicAdd(Sp + m * 128 + n, acc[i][j][r]);   // HW global_atomic_add_f32
                }
    }
    gridbar(a.bar + 1024);

    // ================= P4: combine  out = S~ @ TW_q + bias + residual ========
    // 512 jobs: which=bid>>8, batch=(bid>>6)&3, qq=(bid>>2)&15, dtile=(bid>>1)&1, ihalf=bid&1.
    {
        const int which = bid >> 8, batch = (bid >> 6) & 3, qq = (bid >> 2) & 15;
        const int dtile = (bid >> 1) & 1, ihalf = bid & 1;
        const int d0 = dtile * 128, i0 = ihalf * 64;
        const float* Sm = a.S + ((size_t)(which * 4 + batch) << 14);
        const unsigned short* Bsrc = (which ? a.PQ : a.TW) + (size_t)batch * 524288;
        const float* Bv = which ? a.b_Q : a.b_W;
        const float* R  = (which ? a.detect : a.aim) + (size_t)batch * 524288;
        float* O = (which ? a.out_det : a.out_aim) + (size_t)batch * 524288;

        unsigned short (*As)[72] = (unsigned short (*)[72])lds;               // [64][72]
        unsigned short (*Bs)[72] = (unsigned short (*)[72])(lds + 64 * 72);   // [128][72]

        f32x4 acc[2][4] = {};

        for (int kk = 0; kk < 2; ++kk) {
            const int k0 = kk * 64;
            #pragma unroll
            for (int i = 0; i < 4; ++i) {            // A: 64x64 fp32 = 1024 float4, scale+convert
                int idx = tid + i * 256, row = idx >> 4, c4 = idx & 15;
                float4 v = *(const float4*)(Sm + (size_t)(i0 + row) * 128 + k0 + c4 * 4);
                u16x4 p;
                p[0]=f2bf(v.x * (1.0f/4096.0f)); p[1]=f2bf(v.y * (1.0f/4096.0f));
                p[2]=f2bf(v.z * (1.0f/4096.0f)); p[3]=f2bf(v.w * (1.0f/4096.0f));
                *(u16x4*)&As[row][c4 * 4] = p;
            }
            #pragma unroll
            for (int i = 0; i < 4; ++i) {            // B: gather 64 rows 16k+q, transpose to [d][k]
                int c = tid + i * 256, krow = c >> 4, dc = (c & 15) * 8;
                int gr = 16 * (k0 + krow) + qq;
                u16x8 v = *(const u16x8*)(Bsrc + (size_t)gr * 256 + d0 + dc);
                #pragma unroll
                for (int jj = 0; jj < 8; ++jj) Bs[dc + jj][krow] = v[jj];
            }
            __syncthreads();
            #pragma unroll
            for (int ks = 0; ks < 2; ++ks) {
                bf16x8 af[2], bb[4];
                #pragma unroll
                for (int i = 0; i < 2; ++i) af[i] = ldfrag(&As[wr * 32 + i * 16 + ln][ks * 32 + q * 8]);
                #pragma unroll
                for (int j = 0; j < 4; ++j) bb[j] = ldfrag(&Bs[wc * 64 + j * 16 + ln][ks * 32 + q * 8]);
                #pragma unroll
                for (int i = 0; i < 2; ++i)
                    #pragma unroll
                    for (int j = 0; j < 4; ++j)
                        acc[i][j] = __builtin_amdgcn_mfma_f32_16x16x32_bf16(af[i], bb[j], acc[i][j], 0, 0, 0);
            }
            __syncthreads();
        }

        #pragma unroll
        for (int i = 0; i < 2; ++i)
            #pragma unroll
            for (int j = 0; j < 4; ++j) {
                int d = d0 + wc * 64 + j * 16 + ln;
                float bias = Bv[d];
                #pragma unroll
                for (int r = 0; r < 4; ++r) {
                    int iS = i0 + wr * 32 + i * 16 + q * 4 + r;
                    size_t off = (size_t)(16 * iS + qq) * 256 + d;
                    O[off] = acc[i][j][r] + bias + R[off];
                }
            }
    }
}

extern "C" void kernel_launch(void* const* d_in, const int* in_sizes, int n_in,
                              void* d_out, int out_size, void* d_ws, size_t ws_size,
                              hipStream_t stream)
{
    const size_t TOT = 8192L * 256;   // 2,097,152 elems per tensor

    unsigned short* ws16 = (unsigned short*)d_ws;
    unsigned short* T   = ws16;
    unsigned short* P   = T  + TOT;
    unsigned short* Gd  = P  + TOT;
    unsigned short* Ga  = Gd + TOT;
    unsigned short* TW  = Ga + TOT;             // T @ W^T  bf16 [8192,256]
    unsigned short* PQ  = TW + TOT;             // P @ Q^T  bf16 [8192,256]
    float* S    = (float*)(PQ + TOT);           // [2][4][128][128] fp32 (atomic accum)
    unsigned* bar = (unsigned*)(S + 131072);    // 2 x 1024 uints

    float* out_det = (float*)d_out;
    float* out_aim = out_det + TOT;

    MegaArgs h;
    h.detect = (const float*)d_in[0];
    h.aim    = (const float*)d_in[1];
    h.g_w  = (const float*)d_in[2];  h.b_g  = (const float*)d_in[3];
    h.g2_w = (const float*)d_in[4];  h.b_g2 = (const float*)d_in[5];
    h.th_w = (const float*)d_in[6];  h.b_th = (const float*)d_in[7];
    h.ph_w = (const float*)d_in[8];  h.b_ph = (const float*)d_in[9];
    h.W_w  = (const float*)d_in[10]; h.b_W  = (const float*)d_in[11];
    h.Q_w  = (const float*)d_in[12]; h.b_Q  = (const float*)d_in[13];
    h.T = T; h.P = P; h.Gd = Gd; h.Ga = Ga; h.TW = TW; h.PQ = PQ;
    h.S = S; h.out_aim = out_aim; h.out_det = out_det;
    h.bar = bar;

    // zero S (atomic accumulators) + barrier flags in one capture-legal memset
    hipMemsetAsync(S, 0, 131072 * 4 + 2 * 1024 * 4, stream);
    mega_kernel<<<dim3(512), dim3(256), 0, stream>>>(h);
}